// Round 10
// baseline (257.254 us; speedup 1.0000x reference)
//
#include <hip/hip_runtime.h>
#include <stdint.h>

// Problem constants
#define S_LEN 2048
#define DMODEL 1024
#define NHEAD 16
#define DKH 64
// M for all GEMMs = B*S = 4096, N = K = 1024

typedef __attribute__((ext_vector_type(8))) short short8;
typedef __attribute__((ext_vector_type(4))) short sv4;
typedef __attribute__((ext_vector_type(4))) float fv4;
typedef __attribute__((ext_vector_type(8))) __bf16 bf16x8;
typedef __attribute__((ext_vector_type(4))) float f32x4;

// 0.125 (1/sqrt(DK)) * log2(e): folded into Wq/bq so softmax can use native exp2
#define QSCALE 0.18033688011112042f

static __device__ __forceinline__ short f2bf(float f) {
  unsigned u = __builtin_bit_cast(unsigned, f);
  u = u + 0x7fffu + ((u >> 16) & 1u);   // RNE
  return (short)(u >> 16);
}

static __device__ __forceinline__ bf16x8 ldfrag(const void* p) {
  return __builtin_bit_cast(bf16x8, *(const short8*)p);
}

#define GLL16(gp, lp) __builtin_amdgcn_global_load_lds( \
    (const __attribute__((address_space(1))) unsigned int*)(const void*)(gp), \
    (__attribute__((address_space(3))) unsigned int*)(void*)(lp), 16, 0, 0)

#define WAIT_VMCNT(N) asm volatile("s_waitcnt vmcnt(" #N ")" ::: "memory")
#define WAIT_LGKM0()  asm volatile("s_waitcnt lgkmcnt(0)" ::: "memory")

// ---------------------------------------------------------------------------
// Kernel 1: f32 -> bf16 conversion of q,k,v and Wq,Wk,Wv,Wo.
// ---------------------------------------------------------------------------
__global__ __launch_bounds__(256) void convert_all(
    const float* __restrict__ q, const float* __restrict__ k, const float* __restrict__ v,
    const float* __restrict__ wq, const float* __restrict__ wk, const float* __restrict__ wv,
    const float* __restrict__ wo,
    short* __restrict__ xb, short* __restrict__ wb, short* __restrict__ wob)
{
  const int total = 4194304;
  for (int gid = blockIdx.x * blockDim.x + threadIdx.x; gid < total;
       gid += gridDim.x * blockDim.x) {
    const float* src; short* dst; int off; float scl = 1.0f;
    if (gid < 3145728) {
      int z = gid >> 20;
      off = (gid & 1048575) << 2;
      src = (z == 0) ? q : (z == 1) ? k : v;
      dst = xb + (size_t)z * 4194304;
    } else {
      int g = gid - 3145728;
      int z = g >> 18;
      off = (g & 262143) << 2;
      src = (z == 0) ? wq : (z == 1) ? wk : (z == 2) ? wv : wo;
      dst = (z < 3) ? (wb + (size_t)z * 1048576) : wob;
      if (z == 0) scl = QSCALE;
    }
    fv4 f = *(const fv4*)(src + off);
    sv4 o;
    o.x = f2bf(f.x * scl); o.y = f2bf(f.y * scl);
    o.z = f2bf(f.z * scl); o.w = f2bf(f.w * scl);
    *(sv4*)(dst + off) = o;
  }
}

// ---------------------------------------------------------------------------
// Kernel 2: QKV projections.  128x128 tile, BK=64, 4 waves, PIPELINED:
// double-buffered LDS (64KB), issue next K-tile GLL before compute, counted
// vmcnt(8) (8 = in-flight next-tile loads), raw barriers.  XCD swizzle.
// ---------------------------------------------------------------------------
__global__ __launch_bounds__(256) void gemm_proj(
    const short* __restrict__ Abase, const short* __restrict__ Wbase,
    const float* __restrict__ bias0, const float* __restrict__ bias1,
    const float* __restrict__ bias2, float bscl0,
    short* __restrict__ Cbf)
{
  const int Kd = 1024, Nd = 1024, Md = 4096;
  const int z = blockIdx.z;
  const short* A = Abase + (size_t)z * Md * Kd;
  const short* W = Wbase + (size_t)z * Nd * Kd;
  const float* bias = (z == 0) ? bias0 : (z == 1) ? bias1 : bias2;
  const float bscl = (z == 0) ? bscl0 : 1.0f;

  __shared__ short8 AB[4096];          // 64KB: buf b at b*32KB (As 16KB + Bs 16KB)

  const int tid = threadIdx.x;
  const int w = tid >> 6, lane = tid & 63;
  const int wr = w >> 1, wc = w & 1;
  const int lhi = lane >> 4, llo = lane & 15;
  const int id = blockIdx.x + 8 * blockIdx.y;       // [0,256)
  const int sw = (id & 7) * 32 + (id >> 3);
  const int n0 = (sw & 7) * 128, m0 = (sw >> 3) * 128;

  const f32x4 zero = {0.f, 0.f, 0.f, 0.f};
  f32x4 acc[4][4];
#pragma unroll
  for (int i = 0; i < 4; ++i)
#pragma unroll
    for (int j = 0; j < 4; ++j) acc[i][j] = zero;

  // staging helper (8 GLL16 per thread per K-step)
  auto stage = [&](int buf, int k0) {
#pragma unroll
    for (int inst = 0; inst < 4; ++inst) {
      int ib = w * 4096 + inst * 1024 + lane * 16;
      int row = ib >> 7;
      int colb = (ib & 127) ^ ((row & 7) << 4);
      int col = colb >> 1;
      GLL16(A + (size_t)(m0 + row) * Kd + k0 + col,
            (char*)AB + buf * 32768 + (w * 4096 + inst * 1024));
      GLL16(W + (size_t)(n0 + row) * Kd + k0 + col,
            (char*)AB + buf * 32768 + 16384 + (w * 4096 + inst * 1024));
    }
  };

  stage(0, 0);    // prologue
  for (int kt = 0; kt < 16; ++kt) {
    const int cur = kt & 1, nxt = cur ^ 1;
    if (kt < 15) {
      stage(nxt, (kt + 1) * 64);
      WAIT_VMCNT(8);                     // tile kt arrived; kt+1 in flight
    } else {
      WAIT_VMCNT(0);
    }
    __builtin_amdgcn_s_barrier();        // all waves: tile kt visible
    const char* As = (const char*)AB + cur * 32768;
    const char* Bs = As + 16384;
#pragma unroll
    for (int kk = 0; kk < 2; ++kk) {
      bf16x8 af[4], bfm[4];
#pragma unroll
      for (int t = 0; t < 4; ++t) {
        int arow = wr * 64 + t * 16 + llo;
        int abyte = ((arow << 7) + ((kk * 32 + lhi * 8) << 1)) ^ ((arow & 7) << 4);
        af[t] = ldfrag(As + abyte);
        int brow = wc * 64 + t * 16 + llo;
        int bbyte = ((brow << 7) + ((kk * 32 + lhi * 8) << 1)) ^ ((brow & 7) << 4);
        bfm[t] = ldfrag(Bs + bbyte);
      }
#pragma unroll
      for (int i = 0; i < 4; ++i)
#pragma unroll
        for (int j = 0; j < 4; ++j)
          acc[i][j] = __builtin_amdgcn_mfma_f32_16x16x32_bf16(af[i], bfm[j], acc[i][j], 0, 0, 0);
    }
    __builtin_amdgcn_s_barrier();        // all reads of cur done before overwrite
  }

  // bf16 output: route through LDS for coalesced 16B stores
  short* Co = Cbf + (size_t)z * Md * Nd;
  __syncthreads();
  short* Cs = (short*)AB;
#pragma unroll
  for (int i = 0; i < 4; ++i) {
#pragma unroll
    for (int j = 0; j < 4; ++j) {
      int col = wc * 64 + j * 16 + llo;
      float bv_ = bias[n0 + col] * bscl;
#pragma unroll
      for (int r = 0; r < 4; ++r) {
        int row = wr * 64 + i * 16 + lhi * 4 + r;
        Cs[row * 128 + col] = f2bf(acc[i][j][r] + bv_);
      }
    }
  }
  __syncthreads();
#pragma unroll
  for (int s = 0; s < 8; ++s) {
    int lb = s * 4096 + tid * 16;
    short8 vL = *(const short8*)((const char*)Cs + lb);
    int row = lb >> 8;
    int colb = lb & 255;
    *(short8*)&Co[(size_t)(m0 + row) * Nd + n0 + (colb >> 1)] = vL;
  }
}

// ---------------------------------------------------------------------------
// Kernel 4: output projection.  128x64 tile, f32 out, PIPELINED dbuf
// (48KB, counted vmcnt(6)).  XCD swizzle.
// ---------------------------------------------------------------------------
__global__ __launch_bounds__(256) void gemm_out(
    const short* __restrict__ A, const short* __restrict__ W,
    const float* __restrict__ bias, float* __restrict__ Cf)
{
  const int Kd = 1024, Nd = 1024;

  __shared__ short8 AB[3072];   // 48KB: buf b at b*24KB (As 16KB + Bs 8KB)

  const int tid = threadIdx.x;
  const int w = tid >> 6, lane = tid & 63;
  const int wr = w >> 1, wc = w & 1;
  const int lhi = lane >> 4, llo = lane & 15;
  const int id = blockIdx.x + 16 * blockIdx.y;      // [0,512)
  const int sw = (id & 7) * 64 + (id >> 3);
  const int n0 = (sw & 15) * 64, m0 = (sw >> 4) * 128;

  const f32x4 zero = {0.f, 0.f, 0.f, 0.f};
  f32x4 acc[4][2];
#pragma unroll
  for (int i = 0; i < 4; ++i)
#pragma unroll
    for (int j = 0; j < 2; ++j) acc[i][j] = zero;

  auto stage = [&](int buf, int k0) {
#pragma unroll
    for (int inst = 0; inst < 4; ++inst) {
      int ib = w * 4096 + inst * 1024 + lane * 16;
      int row = ib >> 7;
      int colb = (ib & 127) ^ ((row & 7) << 4);
      GLL16(A + (size_t)(m0 + row) * Kd + k0 + (colb >> 1),
            (char*)AB + buf * 24576 + (w * 4096 + inst * 1024));
    }
#pragma unroll
    for (int inst = 0; inst < 2; ++inst) {
      int ib = w * 2048 + inst * 1024 + lane * 16;
      int row = ib >> 7;
      int colb = (ib & 127) ^ ((row & 7) << 4);
      GLL16(W + (size_t)(n0 + row) * Kd + k0 + (colb >> 1),
            (char*)AB + buf * 24576 + 16384 + (w * 2048 + inst * 1024));
    }
  };

  stage(0, 0);
  for (int kt = 0; kt < 16; ++kt) {
    const int cur = kt & 1, nxt = cur ^ 1;
    if (kt < 15) {
      stage(nxt, (kt + 1) * 64);
      WAIT_VMCNT(6);
    } else {
      WAIT_VMCNT(0);
    }
    __builtin_amdgcn_s_barrier();
    const char* As = (const char*)AB + cur * 24576;
    const char* Bs = As + 16384;
#pragma unroll
    for (int kk = 0; kk < 2; ++kk) {
      bf16x8 af[4], bfm[2];
#pragma unroll
      for (int t = 0; t < 4; ++t) {
        int arow = wr * 64 + t * 16 + llo;
        int abyte = ((arow << 7) + ((kk * 32 + lhi * 8) << 1)) ^ ((arow & 7) << 4);
        af[t] = ldfrag(As + abyte);
      }
#pragma unroll
      for (int j = 0; j < 2; ++j) {
        int brow = wc * 32 + j * 16 + llo;
        int bbyte = ((brow << 7) + ((kk * 32 + lhi * 8) << 1)) ^ ((brow & 7) << 4);
        bfm[j] = ldfrag(Bs + bbyte);
      }
#pragma unroll
      for (int i = 0; i < 4; ++i)
#pragma unroll
        for (int j = 0; j < 2; ++j)
          acc[i][j] = __builtin_amdgcn_mfma_f32_16x16x32_bf16(af[i], bfm[j], acc[i][j], 0, 0, 0);
    }
    __builtin_amdgcn_s_barrier();
  }

#pragma unroll
  for (int i = 0; i < 4; ++i) {
#pragma unroll
    for (int j = 0; j < 2; ++j) {
      int col = n0 + wc * 32 + j * 16 + llo;
      float bv_ = bias[col];
#pragma unroll
      for (int r = 0; r < 4; ++r) {
        int row = m0 + wr * 64 + i * 16 + lhi * 4 + r;
        Cf[(size_t)row * Nd + col] = acc[i][j][r] + bv_;
      }
    }
  }
}

// ---------------------------------------------------------------------------
// Kernel 3: causal flash attention.  QBLK=128 (8 waves x 16 q-rows),
// KVBLK=64.  512 blocks; decode puts blocks {2w, 15-2w} of the SAME (b,h)
// on each CU (stride-256 round-robin) -> uniform 34 tile-iters/CU and
// K/V L2 sharing.  Double-buffered K (GLL, swizzled); single-buffered V^T;
// conflict-free b16 V^T writes (8/thread).  Per tile: vmcnt(0); V^T write;
// issue next loads; lgkm+B1; QK; softmax (T13 defer, deferred l-reduce);
// PV; B2.  Causal mask applies on the last two kv-tiles (t >= nt-2).
// ---------------------------------------------------------------------------
__global__ __launch_bounds__(512) void attn_fwd(
    const short* __restrict__ Qp, const short* __restrict__ Kp,
    const short* __restrict__ Vp, short* __restrict__ Out)
{
  __shared__ short8 Ks[2][512];      // 2 x 64x64 bf16, swizzled (16KB)
  __shared__ short  Vt[64 * 72];     // V^T 64 d-rows x 72-pad (9KB)
  __shared__ short  PsA[8][16 * 72]; // per-wave P (18KB)

  const int tid = threadIdx.x;
  const int w = tid >> 6, lane = tid & 63;
  const int lhi = lane >> 4, llo = lane & 15;

  // 2-set balanced decode: id<256 -> qt even {2w}, else qt odd {15-2w};
  // same bh for paired blocks on one CU.
  const int id = blockIdx.x;
  const int half = id >> 8;          // 0 or 1
  const int g = id & 255;
  const int bh = g >> 3;
  const int wv = g & 7;
  const int qt = half ? (15 - 2 * wv) : (2 * wv);
  const int nt = 2 * qt + 2;         // kv tiles of 64
  const int qbase = qt * 128;
  const int b = bh >> 4, h = bh & 15;
  const size_t rowbase = (size_t)b * S_LEN;
  const short* Kbase = Kp + rowbase * DMODEL + h * DKH;
  const short* Vbase = Vp + rowbase * DMODEL + h * DKH;

  short* Ps = PsA[w];
  const f32x4 zero = {0.f, 0.f, 0.f, 0.f};

  // Q fragments (registers for whole block): wave w owns q-rows qbase+w*16..+15
  bf16x8 qf[2];
  {
    const short* qrow = Qp + (rowbase + qbase + w * 16 + llo) * DMODEL + h * DKH;
    qf[0] = ldfrag(qrow + lhi * 8);
    qf[1] = ldfrag(qrow + 32 + lhi * 8);
  }

  float mr[4], lr[4];
  f32x4 oacc[4];
#pragma unroll
  for (int r = 0; r < 4; ++r) { mr[r] = -3.0e38f; lr[r] = 0.f; }
#pragma unroll
  for (int dt = 0; dt < 4; ++dt) oacc[dt] = zero;

  // V staging: kv = lane, 8 d-values per thread (d = w*8..w*8+7)
  const int kvs = lane;

  // prologue: stage tile 0 (1 GLL16/thread covers the 8KB K-tile)
  {
    int ib = tid * 16;
    int row = ib >> 7;
    int colb = (ib & 127) ^ ((row & 7) << 4);
    GLL16(Kbase + (size_t)row * DMODEL + (colb >> 1), (char*)&Ks[0][0] + ib);
  }
  short8 va = *(const short8*)(Vbase + (size_t)kvs * DMODEL + w * 8);

  for (int t = 0; t < nt; ++t) {
    const int cur = t & 1, nxt = cur ^ 1;
    const int kvbase = t * 64;

    asm volatile("s_waitcnt vmcnt(0)" ::: "memory");  // own K-GLL(t)+va(t) done
#pragma unroll
    for (int j = 0; j < 8; ++j) Vt[(w * 8 + j) * 72 + kvs] = va[j];
    if (t + 1 < nt) {
      const int nb = kvbase + 64;
      int ib = tid * 16;
      int row = ib >> 7;
      int colb = (ib & 127) ^ ((row & 7) << 4);
      GLL16(Kbase + (size_t)(nb + row) * DMODEL + (colb >> 1),
            (char*)&Ks[nxt][0] + ib);
      va = *(const short8*)(Vbase + (size_t)(nb + kvs) * DMODEL + w * 8);
    }
    WAIT_LGKM0();
    __builtin_amdgcn_s_barrier();   // B1: all staging for tile t visible

    // QK^T
    f32x4 sc[4];
#pragma unroll
    for (int tt = 0; tt < 4; ++tt) sc[tt] = zero;
    __builtin_amdgcn_s_setprio(1);
#pragma unroll
    for (int kk = 0; kk < 2; ++kk) {
#pragma unroll
      for (int tt = 0; tt < 4; ++tt) {
        int krow = tt * 16 + llo;
        int kbyte = ((krow << 7) + ((kk * 32 + lhi * 8) << 1)) ^ ((krow & 7) << 4);
        bf16x8 kf = ldfrag((const char*)&Ks[cur][0] + kbyte);
        sc[tt] = __builtin_amdgcn_mfma_f32_16x16x32_bf16(qf[kk], kf, sc[tt], 0, 0, 0);
      }
    }
    __builtin_amdgcn_s_setprio(0);

    // mask (last two tiles only) + tile max
    const bool diag = (t >= nt - 2);
    float sv[4][4], tmx[4];
#pragma unroll
    for (int r = 0; r < 4; ++r) {
#pragma unroll
      for (int tt = 0; tt < 4; ++tt) {
        float s = sc[tt][r];
        if (diag) {
          int kg = kvbase + tt * 16 + llo;
          int qg = qbase + w * 16 + lhi * 4 + r;
          if (kg > qg) s = -3.0e38f;
        }
        sv[tt][r] = s;
      }
      float trm = fmaxf(fmaxf(sv[0][r], sv[1][r]), fmaxf(sv[2][r], sv[3][r]));
      trm = fmaxf(trm, __shfl_xor(trm, 1));
      trm = fmaxf(trm, __shfl_xor(trm, 2));
      trm = fmaxf(trm, __shfl_xor(trm, 4));
      trm = fmaxf(trm, __shfl_xor(trm, 8));
      tmx[r] = trm;
    }
    // T13 defer-rescale
    bool grow = (tmx[0] > mr[0] + 8.f) || (tmx[1] > mr[1] + 8.f) ||
                (tmx[2] > mr[2] + 8.f) || (tmx[3] > mr[3] + 8.f);
    if (__ballot(grow)) {
#pragma unroll
      for (int r = 0; r < 4; ++r) {
        float mnew = fmaxf(mr[r], tmx[r]);
        float alpha = __builtin_amdgcn_exp2f(mr[r] - mnew);
        mr[r] = mnew;
        lr[r] *= alpha;
#pragma unroll
        for (int dt = 0; dt < 4; ++dt) oacc[dt][r] = oacc[dt][r] * alpha;
      }
    }
    // P + per-lane partial l (reduce deferred to end)
#pragma unroll
    for (int r = 0; r < 4; ++r) {
      float rs = 0.f;
#pragma unroll
      for (int tt = 0; tt < 4; ++tt) {
        float pv = __builtin_amdgcn_exp2f(sv[tt][r] - mr[r]);
        rs += pv;
        Ps[(lhi * 4 + r) * 72 + tt * 16 + llo] = f2bf(pv);
      }
      lr[r] += rs;
    }

    // PV
    __builtin_amdgcn_s_setprio(1);
#pragma unroll
    for (int kk = 0; kk < 2; ++kk) {
      bf16x8 pa = ldfrag(Ps + llo * 72 + kk * 32 + lhi * 8);
#pragma unroll
      for (int dt = 0; dt < 4; ++dt) {
        bf16x8 vf = ldfrag(&Vt[(dt * 16 + llo) * 72 + kk * 32 + lhi * 8]);
        oacc[dt] = __builtin_amdgcn_mfma_f32_16x16x32_bf16(pa, vf, oacc[dt], 0, 0, 0);
      }
    }
    __builtin_amdgcn_s_setprio(0);
    __builtin_amdgcn_s_barrier();   // B2: reads of Ks[cur]/Vt done before reuse
  }

  // final l reduction, then direct-store epilogue
#pragma unroll
  for (int r = 0; r < 4; ++r) {
    float rs = lr[r];
    rs += __shfl_xor(rs, 1);
    rs += __shfl_xor(rs, 2);
    rs += __shfl_xor(rs, 4);
    rs += __shfl_xor(rs, 8);
    lr[r] = rs;
  }
#pragma unroll
  for (int dt = 0; dt < 4; ++dt) {
#pragma unroll
    for (int r = 0; r < 4; ++r) {
      float vv = oacc[dt][r] / lr[r];
      int row = qbase + w * 16 + lhi * 4 + r;
      int col = h * DKH + dt * 16 + llo;
      Out[(rowbase + row) * DMODEL + col] = f2bf(vv);
    }
  }
}

// ---------------------------------------------------------------------------
extern "C" void kernel_launch(void* const* d_in, const int* in_sizes, int n_in,
                              void* d_out, int out_size, void* d_ws, size_t ws_size,
                              hipStream_t stream) {
  (void)in_sizes; (void)n_in; (void)out_size; (void)ws_size;
  const float* q  = (const float*)d_in[0];
  const float* k  = (const float*)d_in[1];
  const float* v  = (const float*)d_in[2];
  // d_in[3] = causal mask (structure known, ignored)
  const float* Wq = (const float*)d_in[4];
  const float* bq = (const float*)d_in[5];
  const float* Wk = (const float*)d_in[6];
  const float* bk = (const float*)d_in[7];
  const float* Wv = (const float*)d_in[8];
  const float* bv = (const float*)d_in[9];
  const float* Wo = (const float*)d_in[10];
  const float* bo = (const float*)d_in[11];
  float* out = (float*)d_out;

  // workspace layout (bf16/short units), ~59MB total
  short* xb   = (short*)d_ws;              // 3 * 4194304 (q,k,v bf16)
  short* wb   = xb + 3ull * 4194304;       // 3 * 1048576 (Wq,Wk,Wv bf16; Wq pre-scaled)
  short* wob  = wb + 3ull * 1048576;       // 1048576    (Wo bf16)
  short* proj = wob + 1048576;             // 3 * 4194304 (Q,K,V projected)
  short* attno = xb;                       // reuse xb (free after projections)

  convert_all<<<dim3(2048), dim3(256), 0, stream>>>(q, k, v, Wq, Wk, Wv, Wo, xb, wb, wob);
  gemm_proj<<<dim3(8, 32, 3), dim3(256), 0, stream>>>(xb, wb, bq, bk, bv, QSCALE, proj);
  attn_fwd<<<dim3(512), dim3(512), 0, stream>>>(proj, proj + 4194304ull,
                                                proj + 2ull * 4194304, attno);
  gemm_out<<<dim3(16, 32), dim3(256), 0, stream>>>(attno, wob, bo, out);
}

// Round 11
// 238.523 us; speedup vs baseline: 1.0785x; 1.0785x over previous
//
#include <hip/hip_runtime.h>
#include <stdint.h>

// Problem constants
#define S_LEN 2048
#define DMODEL 1024
#define NHEAD 16
#define DKH 64

typedef __attribute__((ext_vector_type(8))) short short8;
typedef __attribute__((ext_vector_type(4))) short sv4;
typedef __attribute__((ext_vector_type(4))) float fv4;
typedef __attribute__((ext_vector_type(8))) __bf16 bf16x8;
typedef __attribute__((ext_vector_type(4))) float f32x4;
typedef __attribute__((ext_vector_type(2))) unsigned int u32x2;
typedef __attribute__((ext_vector_type(4))) unsigned int u32x4;

// 0.125 (1/sqrt(DK)) * log2(e): folded into Wq/bq so softmax can use native exp2
#define QSCALE 0.18033688011112042f

static __device__ __forceinline__ short f2bf(float f) {
  unsigned u = __builtin_bit_cast(unsigned, f);
  u = u + 0x7fffu + ((u >> 16) & 1u);   // RNE
  return (short)(u >> 16);
}

// packed f32 pair -> bf16 pair (RNE), lo = a, hi = b
static __device__ __forceinline__ unsigned cvtpk(float a, float b) {
  unsigned r;
  asm("v_cvt_pk_bf16_f32 %0, %1, %2" : "=v"(r) : "v"(a), "v"(b));
  return r;
}

static __device__ __forceinline__ bf16x8 ldfrag(const void* p) {
  return __builtin_bit_cast(bf16x8, *(const short8*)p);
}

#define GLL16(gp, lp) __builtin_amdgcn_global_load_lds( \
    (const __attribute__((address_space(1))) unsigned int*)(const void*)(gp), \
    (__attribute__((address_space(3))) unsigned int*)(void*)(lp), 16, 0, 0)

#define WAIT_VMCNT(N) asm volatile("s_waitcnt vmcnt(" #N ")" ::: "memory")
#define WAIT_LGKM0()  asm volatile("s_waitcnt lgkmcnt(0)" ::: "memory")

// ---------------------------------------------------------------------------
// Kernel 1: f32 -> bf16 conversion of q,k,v and Wq,Wk,Wv,Wo.
// ---------------------------------------------------------------------------
__global__ __launch_bounds__(256) void convert_all(
    const float* __restrict__ q, const float* __restrict__ k, const float* __restrict__ v,
    const float* __restrict__ wq, const float* __restrict__ wk, const float* __restrict__ wv,
    const float* __restrict__ wo,
    short* __restrict__ xb, short* __restrict__ wb, short* __restrict__ wob)
{
  const int total = 4194304;
  for (int gid = blockIdx.x * blockDim.x + threadIdx.x; gid < total;
       gid += gridDim.x * blockDim.x) {
    const float* src; short* dst; int off; float scl = 1.0f;
    if (gid < 3145728) {
      int z = gid >> 20;
      off = (gid & 1048575) << 2;
      src = (z == 0) ? q : (z == 1) ? k : v;
      dst = xb + (size_t)z * 4194304;
    } else {
      int g = gid - 3145728;
      int z = g >> 18;
      off = (g & 262143) << 2;
      src = (z == 0) ? wq : (z == 1) ? wk : (z == 2) ? wv : wo;
      dst = (z < 3) ? (wb + (size_t)z * 1048576) : wob;
      if (z == 0) scl = QSCALE;
    }
    fv4 f = *(const fv4*)(src + off);
    sv4 o;
    o.x = f2bf(f.x * scl); o.y = f2bf(f.y * scl);
    o.z = f2bf(f.z * scl); o.w = f2bf(f.w * scl);
    *(sv4*)(dst + off) = o;
  }
}

// ---------------------------------------------------------------------------
// Kernel 2: QKV projections.  128x128 tile, BK=64, 4 waves, pipelined dbuf
// (counted vmcnt(8)).  XCD swizzle.  (unchanged from round 10)
// ---------------------------------------------------------------------------
__global__ __launch_bounds__(256) void gemm_proj(
    const short* __restrict__ Abase, const short* __restrict__ Wbase,
    const float* __restrict__ bias0, const float* __restrict__ bias1,
    const float* __restrict__ bias2, float bscl0,
    short* __restrict__ Cbf)
{
  const int Kd = 1024, Nd = 1024, Md = 4096;
  const int z = blockIdx.z;
  const short* A = Abase + (size_t)z * Md * Kd;
  const short* W = Wbase + (size_t)z * Nd * Kd;
  const float* bias = (z == 0) ? bias0 : (z == 1) ? bias1 : bias2;
  const float bscl = (z == 0) ? bscl0 : 1.0f;

  __shared__ short8 AB[4096];          // 64KB dbuf

  const int tid = threadIdx.x;
  const int w = tid >> 6, lane = tid & 63;
  const int wr = w >> 1, wc = w & 1;
  const int lhi = lane >> 4, llo = lane & 15;
  const int id = blockIdx.x + 8 * blockIdx.y;
  const int sw = (id & 7) * 32 + (id >> 3);
  const int n0 = (sw & 7) * 128, m0 = (sw >> 3) * 128;

  const f32x4 zero = {0.f, 0.f, 0.f, 0.f};
  f32x4 acc[4][4];
#pragma unroll
  for (int i = 0; i < 4; ++i)
#pragma unroll
    for (int j = 0; j < 4; ++j) acc[i][j] = zero;

  auto stage = [&](int buf, int k0) {
#pragma unroll
    for (int inst = 0; inst < 4; ++inst) {
      int ib = w * 4096 + inst * 1024 + lane * 16;
      int row = ib >> 7;
      int colb = (ib & 127) ^ ((row & 7) << 4);
      int col = colb >> 1;
      GLL16(A + (size_t)(m0 + row) * Kd + k0 + col,
            (char*)AB + buf * 32768 + (w * 4096 + inst * 1024));
      GLL16(W + (size_t)(n0 + row) * Kd + k0 + col,
            (char*)AB + buf * 32768 + 16384 + (w * 4096 + inst * 1024));
    }
  };

  stage(0, 0);
  for (int kt = 0; kt < 16; ++kt) {
    const int cur = kt & 1, nxt = cur ^ 1;
    if (kt < 15) {
      stage(nxt, (kt + 1) * 64);
      WAIT_VMCNT(8);
    } else {
      WAIT_VMCNT(0);
    }
    __builtin_amdgcn_s_barrier();
    const char* As = (const char*)AB + cur * 32768;
    const char* Bs = As + 16384;
#pragma unroll
    for (int kk = 0; kk < 2; ++kk) {
      bf16x8 af[4], bfm[4];
#pragma unroll
      for (int t = 0; t < 4; ++t) {
        int arow = wr * 64 + t * 16 + llo;
        int abyte = ((arow << 7) + ((kk * 32 + lhi * 8) << 1)) ^ ((arow & 7) << 4);
        af[t] = ldfrag(As + abyte);
        int brow = wc * 64 + t * 16 + llo;
        int bbyte = ((brow << 7) + ((kk * 32 + lhi * 8) << 1)) ^ ((brow & 7) << 4);
        bfm[t] = ldfrag(Bs + bbyte);
      }
#pragma unroll
      for (int i = 0; i < 4; ++i)
#pragma unroll
        for (int j = 0; j < 4; ++j)
          acc[i][j] = __builtin_amdgcn_mfma_f32_16x16x32_bf16(af[i], bfm[j], acc[i][j], 0, 0, 0);
    }
    __builtin_amdgcn_s_barrier();
  }

  short* Co = Cbf + (size_t)z * Md * Nd;
  __syncthreads();
  short* Cs = (short*)AB;
#pragma unroll
  for (int i = 0; i < 4; ++i) {
#pragma unroll
    for (int j = 0; j < 4; ++j) {
      int col = wc * 64 + j * 16 + llo;
      float bv_ = bias[n0 + col] * bscl;
#pragma unroll
      for (int r = 0; r < 4; ++r) {
        int row = wr * 64 + i * 16 + lhi * 4 + r;
        Cs[row * 128 + col] = f2bf(acc[i][j][r] + bv_);
      }
    }
  }
  __syncthreads();
#pragma unroll
  for (int s = 0; s < 8; ++s) {
    int lb = s * 4096 + tid * 16;
    short8 vL = *(const short8*)((const char*)Cs + lb);
    int row = lb >> 8;
    int colb = lb & 255;
    *(short8*)&Co[(size_t)(m0 + row) * Nd + n0 + (colb >> 1)] = vL;
  }
}

// ---------------------------------------------------------------------------
// Kernel 4: output projection.  128x64 tile, f32 out, pipelined dbuf
// (counted vmcnt(6)).  XCD swizzle.  (unchanged from round 10)
// ---------------------------------------------------------------------------
__global__ __launch_bounds__(256) void gemm_out(
    const short* __restrict__ A, const short* __restrict__ W,
    const float* __restrict__ bias, float* __restrict__ Cf)
{
  const int Kd = 1024, Nd = 1024;

  __shared__ short8 AB[3072];   // 48KB dbuf

  const int tid = threadIdx.x;
  const int w = tid >> 6, lane = tid & 63;
  const int wr = w >> 1, wc = w & 1;
  const int lhi = lane >> 4, llo = lane & 15;
  const int id = blockIdx.x + 16 * blockIdx.y;
  const int sw = (id & 7) * 64 + (id >> 3);
  const int n0 = (sw & 15) * 64, m0 = (sw >> 4) * 128;

  const f32x4 zero = {0.f, 0.f, 0.f, 0.f};
  f32x4 acc[4][2];
#pragma unroll
  for (int i = 0; i < 4; ++i)
#pragma unroll
    for (int j = 0; j < 2; ++j) acc[i][j] = zero;

  auto stage = [&](int buf, int k0) {
#pragma unroll
    for (int inst = 0; inst < 4; ++inst) {
      int ib = w * 4096 + inst * 1024 + lane * 16;
      int row = ib >> 7;
      int colb = (ib & 127) ^ ((row & 7) << 4);
      GLL16(A + (size_t)(m0 + row) * Kd + k0 + (colb >> 1),
            (char*)AB + buf * 24576 + (w * 4096 + inst * 1024));
    }
#pragma unroll
    for (int inst = 0; inst < 2; ++inst) {
      int ib = w * 2048 + inst * 1024 + lane * 16;
      int row = ib >> 7;
      int colb = (ib & 127) ^ ((row & 7) << 4);
      GLL16(W + (size_t)(n0 + row) * Kd + k0 + (colb >> 1),
            (char*)AB + buf * 24576 + 16384 + (w * 2048 + inst * 1024));
    }
  };

  stage(0, 0);
  for (int kt = 0; kt < 16; ++kt) {
    const int cur = kt & 1, nxt = cur ^ 1;
    if (kt < 15) {
      stage(nxt, (kt + 1) * 64);
      WAIT_VMCNT(6);
    } else {
      WAIT_VMCNT(0);
    }
    __builtin_amdgcn_s_barrier();
    const char* As = (const char*)AB + cur * 24576;
    const char* Bs = As + 16384;
#pragma unroll
    for (int kk = 0; kk < 2; ++kk) {
      bf16x8 af[4], bfm[2];
#pragma unroll
      for (int t = 0; t < 4; ++t) {
        int arow = wr * 64 + t * 16 + llo;
        int abyte = ((arow << 7) + ((kk * 32 + lhi * 8) << 1)) ^ ((arow & 7) << 4);
        af[t] = ldfrag(As + abyte);
      }
#pragma unroll
      for (int j = 0; j < 2; ++j) {
        int brow = wc * 32 + j * 16 + llo;
        int bbyte = ((brow << 7) + ((kk * 32 + lhi * 8) << 1)) ^ ((brow & 7) << 4);
        bfm[j] = ldfrag(Bs + bbyte);
      }
#pragma unroll
      for (int i = 0; i < 4; ++i)
#pragma unroll
        for (int j = 0; j < 2; ++j)
          acc[i][j] = __builtin_amdgcn_mfma_f32_16x16x32_bf16(af[i], bfm[j], acc[i][j], 0, 0, 0);
    }
    __builtin_amdgcn_s_barrier();
  }

#pragma unroll
  for (int i = 0; i < 4; ++i) {
#pragma unroll
    for (int j = 0; j < 2; ++j) {
      int col = n0 + wc * 32 + j * 16 + llo;
      float bv_ = bias[col];
#pragma unroll
      for (int r = 0; r < 4; ++r) {
        int row = m0 + wr * 64 + i * 16 + lhi * 4 + r;
        Cf[(size_t)row * Nd + col] = acc[i][j][r] + bv_;
      }
    }
  }
}

// ---------------------------------------------------------------------------
// Kernel 3: causal flash attention, SWAPPED-OPERAND core (T12 structure).
// Shell = round 8: QBLK=64, 4 waves, 1024 blocks, 4-set balance, K-GLL dbuf
// pipeline, single-buffered V^T.  LDS 25.3KB (P never touches LDS).
//
// QK^T computed as mfma(K, Q) -> sc[tt]: row=kv(tt*16+lhi*4+r), col=q(llo).
// Each lane owns ONE q-row (llo) with 16 kv slots -> mr/lr are lane scalars;
// row-max = in-lane tree + shfl_xor(16,32).  P stays in registers:
// 8 cvt_pk + 16 shfl + 8 selects rebuild the PV B-fragment
// (dest (llo,lhi) kv=kk*32+lhi*8+j  <=  src lane (2*(lhi&1)+c)*16+llo,
//  tile tt=2*kk+(lhi>>1), pair c=j>>2 — bijective).
// PV = mfma(V^T, P^T) -> O^T: row=d(dt*16+lhi*4+r), col=q(llo).
// ---------------------------------------------------------------------------
__global__ __launch_bounds__(256) void attn_fwd(
    const short* __restrict__ Qp, const short* __restrict__ Kp,
    const short* __restrict__ Vp, short* __restrict__ Out)
{
  __shared__ short8 Ks[2][512];      // 2 x 64x64 bf16, swizzled (16KB)
  __shared__ short  Vt[64 * 72];     // V^T 64 d-rows x 72-pad (9KB)

  const int tid = threadIdx.x;
  const int w = tid >> 6, lane = tid & 63;
  const int lhi = lane >> 4, llo = lane & 15;

  // 4-set balanced decode (round 8)
  const int id = blockIdx.x;
  const int g  = id & 255;
  const int kq = id >> 8;
  const int wv = g & 7;
  const int bh = g >> 3;
  const int qt = (kq == 0) ? 2 * wv : (kq == 1) ? 31 - 2 * wv
               : (kq == 2) ? 2 * wv + 1 : 30 - 2 * wv;
  const int nt = qt + 1;
  const int qbase = qt * 64;
  const int b = bh >> 4, h = bh & 15;
  const size_t rowbase = (size_t)b * S_LEN;
  const short* Kbase = Kp + rowbase * DMODEL + h * DKH;
  const short* Vbase = Vp + rowbase * DMODEL + h * DKH;

  const f32x4 zero = {0.f, 0.f, 0.f, 0.f};

  // Q fragments: lane (llo,lhi) holds Q[q=qbase+w*16+llo][d=kk*32+lhi*8+j]
  bf16x8 qf[2];
  {
    const short* qrow = Qp + (rowbase + qbase + w * 16 + llo) * DMODEL + h * DKH;
    qf[0] = ldfrag(qrow + lhi * 8);
    qf[1] = ldfrag(qrow + 32 + lhi * 8);
  }

  float mr = -3.0e38f, lr = 0.f;     // lane scalars (one q-row per lane)
  f32x4 oacc[4];                     // O^T[d=dt*16+lhi*4+r][q=llo]
#pragma unroll
  for (int dt = 0; dt < 4; ++dt) oacc[dt] = zero;

  // V staging: kv = lane, d-group = wave (16 d per thread)
  const int kvs = lane, dgrp = w;

  // shuffle sources for the P redistribution (constant per lane)
  const int srcA = (2 * (lhi & 1)) * 16 + llo;
  const int srcB = srcA + 16;
  const int t0d = lhi >> 1;

  // prologue: stage tile 0
#pragma unroll
  for (int inst = 0; inst < 2; ++inst) {
    int ib = w * 2048 + inst * 1024 + lane * 16;
    int row = ib >> 7;
    int colb = (ib & 127) ^ ((row & 7) << 4);
    GLL16(Kbase + (size_t)row * DMODEL + (colb >> 1),
          (char*)&Ks[0][0] + (w * 2048 + inst * 1024));
  }
  short8 va, vb;
  va = *(const short8*)(Vbase + (size_t)kvs * DMODEL + dgrp * 16);
  vb = *(const short8*)(Vbase + (size_t)kvs * DMODEL + dgrp * 16 + 8);

  for (int t = 0; t < nt; ++t) {
    const int cur = t & 1, nxt = cur ^ 1;
    const int kvbase = t * 64;

    WAIT_VMCNT(0);   // own K-GLL(t) + V-regs(t) complete
#pragma unroll
    for (int j = 0; j < 8; ++j) Vt[(dgrp * 16 + j) * 72 + kvs] = va[j];
#pragma unroll
    for (int j = 0; j < 8; ++j) Vt[(dgrp * 16 + 8 + j) * 72 + kvs] = vb[j];
    if (t + 1 < nt) {
      const int nb = kvbase + 64;
#pragma unroll
      for (int inst = 0; inst < 2; ++inst) {
        int ib = w * 2048 + inst * 1024 + lane * 16;
        int row = ib >> 7;
        int colb = (ib & 127) ^ ((row & 7) << 4);
        GLL16(Kbase + (size_t)(nb + row) * DMODEL + (colb >> 1),
              (char*)&Ks[nxt][0] + (w * 2048 + inst * 1024));
      }
      va = *(const short8*)(Vbase + (size_t)(nb + kvs) * DMODEL + dgrp * 16);
      vb = *(const short8*)(Vbase + (size_t)(nb + kvs) * DMODEL + dgrp * 16 + 8);
    }
    WAIT_LGKM0();
    __builtin_amdgcn_s_barrier();   // B1: staging for tile t visible

    // QK^T swapped: sc[tt] = K(tt-block) . Q^T -> row=kv, col=q
    f32x4 sc[4];
#pragma unroll
    for (int tt = 0; tt < 4; ++tt) sc[tt] = zero;
    __builtin_amdgcn_s_setprio(1);
#pragma unroll
    for (int kk = 0; kk < 2; ++kk) {
#pragma unroll
      for (int tt = 0; tt < 4; ++tt) {
        int krow = tt * 16 + llo;
        int kbyte = ((krow << 7) + ((kk * 32 + lhi * 8) << 1)) ^ ((krow & 7) << 4);
        bf16x8 kf = ldfrag((const char*)&Ks[cur][0] + kbyte);
        sc[tt] = __builtin_amdgcn_mfma_f32_16x16x32_bf16(kf, qf[kk], sc[tt], 0, 0, 0);
      }
    }
    __builtin_amdgcn_s_setprio(0);

    // mask (diag tile) + in-lane max over 16 kv slots
    const bool diag = (t == qt);
    float sv[4][4];
#pragma unroll
    for (int tt = 0; tt < 4; ++tt) {
#pragma unroll
      for (int r = 0; r < 4; ++r) {
        float s = sc[tt][r];
        if (diag) {
          int kg = kvbase + tt * 16 + lhi * 4 + r;
          int qg = qbase + w * 16 + llo;
          if (kg > qg) s = -3.0e38f;
        }
        sv[tt][r] = s;
      }
    }
    float pmax = -3.0e38f;
#pragma unroll
    for (int tt = 0; tt < 4; ++tt)
      pmax = fmaxf(pmax, fmaxf(fmaxf(sv[tt][0], sv[tt][1]),
                               fmaxf(sv[tt][2], sv[tt][3])));
    pmax = fmaxf(pmax, __shfl_xor(pmax, 16));
    pmax = fmaxf(pmax, __shfl_xor(pmax, 32));

    // T13 defer-rescale (THR=8)
    if (__ballot(pmax > mr + 8.f)) {
      float mnew = fmaxf(mr, pmax);
      float alpha = __builtin_amdgcn_exp2f(mr - mnew);
      mr = mnew;
      lr *= alpha;
#pragma unroll
      for (int dt = 0; dt < 4; ++dt) oacc[dt] = oacc[dt] * alpha;
    }

    // exp2 + partial l + in-register pack
    float p[4][4];
#pragma unroll
    for (int tt = 0; tt < 4; ++tt)
#pragma unroll
      for (int r = 0; r < 4; ++r) {
        p[tt][r] = __builtin_amdgcn_exp2f(sv[tt][r] - mr);
        lr += p[tt][r];
      }
    unsigned plo[4], phi[4];
#pragma unroll
    for (int tt = 0; tt < 4; ++tt) {
      plo[tt] = cvtpk(p[tt][0], p[tt][1]);
      phi[tt] = cvtpk(p[tt][2], p[tt][3]);
    }

    // PV: oacc[dt] = mfma(V^T(dt-block), P^T) -> O^T
    __builtin_amdgcn_s_setprio(1);
#pragma unroll
    for (int kk = 0; kk < 2; ++kk) {
      unsigned aL0 = __shfl((int)plo[2 * kk + 0], srcA);
      unsigned aH0 = __shfl((int)phi[2 * kk + 0], srcA);
      unsigned aL1 = __shfl((int)plo[2 * kk + 1], srcA);
      unsigned aH1 = __shfl((int)phi[2 * kk + 1], srcA);
      unsigned bL0 = __shfl((int)plo[2 * kk + 0], srcB);
      unsigned bH0 = __shfl((int)phi[2 * kk + 0], srcB);
      unsigned bL1 = __shfl((int)plo[2 * kk + 1], srcB);
      unsigned bH1 = __shfl((int)phi[2 * kk + 1], srcB);
      u32x4 pw;
      pw.x = t0d ? aL1 : aL0;   // j = 0,1
      pw.y = t0d ? aH1 : aH0;   // j = 2,3
      pw.z = t0d ? bL1 : bL0;   // j = 4,5
      pw.w = t0d ? bH1 : bH0;   // j = 6,7
      bf16x8 pb = __builtin_bit_cast(bf16x8, pw);
#pragma unroll
      for (int dt = 0; dt < 4; ++dt) {
        bf16x8 vf = ldfrag(&Vt[(dt * 16 + llo) * 72 + kk * 32 + lhi * 8]);
        oacc[dt] = __builtin_amdgcn_mfma_f32_16x16x32_bf16(vf, pb, oacc[dt], 0, 0, 0);
      }
    }
    __builtin_amdgcn_s_setprio(0);
    __builtin_amdgcn_s_barrier();   // B2: reads of Ks[cur]/Vt done before reuse
  }

  // final l reduction across the 4 lhi groups, then packed store of O^T
  lr += __shfl_xor(lr, 16);
  lr += __shfl_xor(lr, 32);
  float inv = 1.0f / lr;
  {
    short* orow = Out + (rowbase + qbase + w * 16 + llo) * DMODEL + h * DKH;
#pragma unroll
    for (int dt = 0; dt < 4; ++dt) {
      u32x2 st;
      st.x = cvtpk(oacc[dt][0] * inv, oacc[dt][1] * inv);
      st.y = cvtpk(oacc[dt][2] * inv, oacc[dt][3] * inv);
      *(u32x2*)&orow[dt * 16 + lhi * 4] = st;
    }
  }
}

// ---------------------------------------------------------------------------
extern "C" void kernel_launch(void* const* d_in, const int* in_sizes, int n_in,
                              void* d_out, int out_size, void* d_ws, size_t ws_size,
                              hipStream_t stream) {
  (void)in_sizes; (void)n_in; (void)out_size; (void)ws_size;
  const float* q  = (const float*)d_in[0];
  const float* k  = (const float*)d_in[1];
  const float* v  = (const float*)d_in[2];
  // d_in[3] = causal mask (structure known, ignored)
  const float* Wq = (const float*)d_in[4];
  const float* bq = (const float*)d_in[5];
  const float* Wk = (const float*)d_in[6];
  const float* bk = (const float*)d_in[7];
  const float* Wv = (const float*)d_in[8];
  const float* bv = (const float*)d_in[9];
  const float* Wo = (const float*)d_in[10];
  const float* bo = (const float*)d_in[11];
  float* out = (float*)d_out;

  // workspace layout (bf16/short units), ~59MB total
  short* xb   = (short*)d_ws;              // 3 * 4194304 (q,k,v bf16)
  short* wb   = xb + 3ull * 4194304;       // 3 * 1048576 (Wq,Wk,Wv bf16; Wq pre-scaled)
  short* wob  = wb + 3ull * 1048576;       // 1048576    (Wo bf16)
  short* proj = wob + 1048576;             // 3 * 4194304 (Q,K,V projected)
  short* attno = xb;                       // reuse xb (free after projections)

  convert_all<<<dim3(2048), dim3(256), 0, stream>>>(q, k, v, Wq, Wk, Wv, Wo, xb, wb, wob);
  gemm_proj<<<dim3(8, 32, 3), dim3(256), 0, stream>>>(xb, wb, bq, bk, bv, QSCALE, proj);
  attn_fwd<<<dim3(1024), dim3(256), 0, stream>>>(proj, proj + 4194304ull,
                                                 proj + 2ull * 4194304, attno);
  gemm_out<<<dim3(16, 32), dim3(256), 0, stream>>>(attno, wob, bo, out);
}